// Round 14
// baseline (2697.446 us; speedup 1.0000x reference)
//
#include <hip/hip_runtime.h>

#define T_STEPS 512
#define BATCH   64
#define IN      512
#define HID     1024
#define GDIM    4096
#define MROWS   (T_STEPS * BATCH)
#define RING    64
#define SENTW   0x7F7F7F7Fu

typedef __attribute__((ext_vector_type(8))) short bf16x8_t;
typedef __attribute__((ext_vector_type(4))) float f32x4_t;

__device__ __forceinline__ unsigned short f2bf(float f) {
  union { float f; unsigned int u; } v; v.f = f;
  unsigned int r = v.u + 0x7FFFu + ((v.u >> 16) & 1u);
  return (unsigned short)(r >> 16);
}
__device__ __forceinline__ float bf2f(unsigned short u) {
  union { unsigned int u; float f; } v; v.u = ((unsigned int)u) << 16;
  return v.f;
}
__device__ __forceinline__ float sigmoidf_(float x) {
  return 1.0f / (1.0f + __expf(-x));
}
__device__ __forceinline__ float tanhf_(float x) {
  return 1.0f - 2.0f / (__expf(2.0f * x) + 1.0f);
}
__device__ __forceinline__ f32x4_t MFMA_(bf16x8_t a, bf16x8_t b, f32x4_t c) {
  return __builtin_amdgcn_mfma_f32_16x16x32_bf16(a, b, c, 0, 0, 0);
}

// ---------------- fp32 -> bf16 conversion ----------------
__global__ void k_cvt(const float* __restrict__ src, unsigned short* __restrict__ dst, int n) {
  int i = (blockIdx.x * blockDim.x + threadIdx.x) * 4;
  if (i + 3 < n) {
    float4 f = *(const float4*)(src + i);
    ushort4 o;
    o.x = f2bf(f.x); o.y = f2bf(f.y); o.z = f2bf(f.z); o.w = f2bf(f.w);
    *(ushort4*)(dst + i) = o;
  }
}

__global__ void k_bias(const float* __restrict__ a, const float* __restrict__ b,
                       float* __restrict__ o) {
  int i = blockIdx.x * blockDim.x + threadIdx.x;
  if (i < GDIM) o[i] = a[i] + b[i];
}

// ---------------- x_proj GEMM: [32768 x 512] @ W_ih^T -> bf16 [32768 x 4096] ----------------
__global__ __launch_bounds__(256) void k_xproj(
    const float* __restrict__ x,
    const unsigned short* __restrict__ Wih,
    const float* __restrict__ bias,
    unsigned short* __restrict__ xproj)
{
  const int AP = 40;
  __shared__ unsigned short Alds[128 * AP];
  __shared__ unsigned short Blds[128 * AP];
  const int tid = threadIdx.x;
  const int w = tid >> 6, l = tid & 63;
  const int m0 = blockIdx.y * 128, n0 = blockIdx.x * 128;
  const int wm = (w >> 1) * 64, wn = (w & 1) * 64;
  f32x4_t acc[4][4] = {};

  for (int k0 = 0; k0 < IN; k0 += 32) {
    #pragma unroll
    for (int it = 0; it < 2; ++it) {
      int chunk = tid + it * 256;
      int row = chunk >> 2;
      int kc  = (chunk & 3) * 8;
      const float* src = x + (size_t)(m0 + row) * IN + k0 + kc;
      float4 f0 = *(const float4*)(src);
      float4 f1 = *(const float4*)(src + 4);
      union { bf16x8_t v; unsigned short s[8]; } u;
      u.s[0]=f2bf(f0.x); u.s[1]=f2bf(f0.y); u.s[2]=f2bf(f0.z); u.s[3]=f2bf(f0.w);
      u.s[4]=f2bf(f1.x); u.s[5]=f2bf(f1.y); u.s[6]=f2bf(f1.z); u.s[7]=f2bf(f1.w);
      *(bf16x8_t*)&Alds[row * AP + kc] = u.v;
    }
    #pragma unroll
    for (int it = 0; it < 2; ++it) {
      int chunk = tid + it * 256;
      int row = chunk >> 2;
      int kc  = (chunk & 3) * 8;
      *(bf16x8_t*)&Blds[row * AP + kc] =
          *(const bf16x8_t*)(Wih + (size_t)(n0 + row) * IN + k0 + kc);
    }
    __syncthreads();
    bf16x8_t a[4], b[4];
    #pragma unroll
    for (int i = 0; i < 4; ++i)
      a[i] = *(const bf16x8_t*)&Alds[(wm + i * 16 + (l & 15)) * AP + ((l >> 4) * 8)];
    #pragma unroll
    for (int i = 0; i < 4; ++i)
      b[i] = *(const bf16x8_t*)&Blds[(wn + i * 16 + (l & 15)) * AP + ((l >> 4) * 8)];
    #pragma unroll
    for (int mi = 0; mi < 4; ++mi) {
      #pragma unroll
      for (int ni = 0; ni < 4; ++ni)
        acc[mi][ni] = MFMA_(a[mi], b[ni], acc[mi][ni]);
    }
    __syncthreads();
  }
  #pragma unroll
  for (int ni = 0; ni < 4; ++ni) {
    int col = n0 + wn + ni * 16 + (l & 15);
    float bv = bias[col];
    #pragma unroll
    for (int mi = 0; mi < 4; ++mi) {
      int rbase = m0 + wm + mi * 16 + (l >> 4) * 4;
      #pragma unroll
      for (int r = 0; r < 4; ++r)
        xproj[(size_t)(rbase + r) * GDIM + col] = f2bf(acc[mi][ni][r] + bv);
    }
  }
}

// ---------------- persistent recurrence kernel (cooperative, 2 chains/block) ----------------
// 128 blocks x 256 threads: blockIdx = pair*32 + slot; pair 0..3 serves
// chains A = pair*2 (batches [pair*16,+8)) and B = pair*2+1 ([pair*16+8,+8)).
// Block owns hidden cols [slot*32,+32) x 4 gates for BOTH chains; the W_hh
// fragments are shared (same cols). Per iteration: pollA -> issue B h-loads
// -> stageA -> MFMA A -> validate+stageB (loads flew under A's work) ->
// epilogueA+publishA -> MFMA B -> epilogueB+publishB. Each chain's exchange
// RTT hides under the other chain's compute. Sentinel-ring exchange (R12-
// proven): relaxed-agent packed stores; consumers poll the data itself.
__global__ __launch_bounds__(256, 1) void k_lstm_persist(
    const unsigned short* __restrict__ xproj,
    const unsigned short* __restrict__ Whh,
    unsigned short* __restrict__ ring,
    float* __restrict__ out,
    float* __restrict__ hT,
    float* __restrict__ cT)
{
  __shared__ __align__(16) unsigned short Hlds[16384];  // 16x1024 bf16; rows 8..15 stay zero
  __shared__ float Glds[4][8][33];

  const int tid = threadIdx.x;
  const int w = tid >> 6, l = tid & 63;
  const int pair = blockIdx.x >> 5;     // 0..3
  const int slot = blockIdx.x & 31;     // col slice 0..31 (32 cols each)
  const int n0  = slot * 32;
  const int b0A = pair * 16;            // chain A batches
  const int b0B = pair * 16 + 8;        // chain B batches

  // zero H tile once (rows 8..15 remain zero forever; h(-1)=0 for t=0)
  {
    bf16x8_t zv = {0, 0, 0, 0, 0, 0, 0, 0};
    #pragma unroll
    for (int i = 0; i < 8; ++i)
      *(bf16x8_t*)((char*)Hlds + (size_t)(i * 256 + tid) * 16) = zv;
  }
  __syncthreads();

  // W_hh fragments: gate w, col-tiles [n0,+16) and [n0+16,+16); shared by A,B
  bf16x8_t wf[64];
  {
    const unsigned short* wp0 =
        Whh + (size_t)((w << 10) + n0 + (l & 15)) * HID + ((l >> 4) * 8);
    const unsigned short* wp1 = wp0 + (size_t)16 * HID;
    #pragma unroll
    for (int ks = 0; ks < 32; ++ks) {
      wf[ks]      = *(const bf16x8_t*)(wp0 + ks * 32);
      wf[32 + ks] = *(const bf16x8_t*)(wp1 + ks * 32);
    }
  }

  // elementwise ids: 256 threads <-> 8 batches x 32 cols (per chain)
  const int eb = tid >> 5, en = tid & 31;
  const size_t ciA = (size_t)(b0A + eb) * HID + n0 + en;
  const size_t ciB = (size_t)(b0B + eb) * HID + n0 + en;
  float cregA = 0.0f, cregB = 0.0f;

  const int abase = (l & 15) * 2048 + ((l >> 4) * 16);
  const int amask = (l & 7) << 4;

  #pragma unroll 1
  for (int t = 0; t < T_STEPS; ++t) {
    // xp values for both chains: plain cached loads, issued early
    const unsigned short* xpA = xproj + ((size_t)t * BATCH + b0A + eb) * GDIM + n0 + en;
    const unsigned short* xpB = xproj + ((size_t)t * BATCH + b0B + eb) * GDIM + n0 + en;
    unsigned short xA0 = xpA[0], xA1 = xpA[1024], xA2 = xpA[2048], xA3 = xpA[3072];
    unsigned short xB0 = xpB[0], xB1 = xpB[1024], xB2 = xpB[2048], xB3 = xpB[3072];
    asm volatile("" ::: "memory");

    union HV { bf16x8_t v; unsigned int u[4]; };
    HV hvB0, hvB1, hvB2, hvB3;   // named (rule #20: no runtime-indexed arrays)
    const char* rsrcB = (const char*)(ring +
        ((size_t)((t - 1) & (RING - 1)) * BATCH + b0B) * HID);

    if (t > 0) {
      // ---- poll chain A: sentinel-validated load (the load IS detection) ----
      const char* rsrcA = (const char*)(ring +
          ((size_t)((t - 1) & (RING - 1)) * BATCH + b0A) * HID);
      HV hvA0, hvA1, hvA2, hvA3;
      unsigned int need = 1u;
      do {
        asm volatile("global_load_dwordx4 %0, %1, off sc0 sc1" : "=v"(hvA0.v)
                     : "v"((unsigned long long)(rsrcA + (size_t)(0 * 256 + tid) * 16)) : "memory");
        asm volatile("global_load_dwordx4 %0, %1, off sc0 sc1" : "=v"(hvA1.v)
                     : "v"((unsigned long long)(rsrcA + (size_t)(1 * 256 + tid) * 16)) : "memory");
        asm volatile("global_load_dwordx4 %0, %1, off sc0 sc1" : "=v"(hvA2.v)
                     : "v"((unsigned long long)(rsrcA + (size_t)(2 * 256 + tid) * 16)) : "memory");
        asm volatile("global_load_dwordx4 %0, %1, off sc0 sc1" : "=v"(hvA3.v)
                     : "v"((unsigned long long)(rsrcA + (size_t)(3 * 256 + tid) * 16)) : "memory");
        asm volatile("s_waitcnt vmcnt(0)" ::: "memory");
        unsigned int bad = 0;
        bad |= (hvA0.u[0]==SENTW)|(hvA0.u[1]==SENTW)|(hvA0.u[2]==SENTW)|(hvA0.u[3]==SENTW);
        bad |= (hvA1.u[0]==SENTW)|(hvA1.u[1]==SENTW)|(hvA1.u[2]==SENTW)|(hvA1.u[3]==SENTW);
        bad |= (hvA2.u[0]==SENTW)|(hvA2.u[1]==SENTW)|(hvA2.u[2]==SENTW)|(hvA2.u[3]==SENTW);
        bad |= (hvA3.u[0]==SENTW)|(hvA3.u[1]==SENTW)|(hvA3.u[2]==SENTW)|(hvA3.u[3]==SENTW);
        need = bad;
        if (need) __builtin_amdgcn_s_sleep(1);
      } while (need);

      // ---- issue chain B's h-loads: fly during A's stage+MFMA ----
      asm volatile("global_load_dwordx4 %0, %1, off sc0 sc1" : "=v"(hvB0.v)
                   : "v"((unsigned long long)(rsrcB + (size_t)(0 * 256 + tid) * 16)) : "memory");
      asm volatile("global_load_dwordx4 %0, %1, off sc0 sc1" : "=v"(hvB1.v)
                   : "v"((unsigned long long)(rsrcB + (size_t)(1 * 256 + tid) * 16)) : "memory");
      asm volatile("global_load_dwordx4 %0, %1, off sc0 sc1" : "=v"(hvB2.v)
                   : "v"((unsigned long long)(rsrcB + (size_t)(2 * 256 + tid) * 16)) : "memory");
      asm volatile("global_load_dwordx4 %0, %1, off sc0 sc1" : "=v"(hvB3.v)
                   : "v"((unsigned long long)(rsrcB + (size_t)(3 * 256 + tid) * 16)) : "memory");

      // ---- stage chain A into LDS (swizzled) ----
      __builtin_amdgcn_sched_barrier(0);
      {
        int d0 = (0 * 256 + tid) * 16, d1 = (1 * 256 + tid) * 16;
        int d2 = (2 * 256 + tid) * 16, d3 = (3 * 256 + tid) * 16;
        *(bf16x8_t*)((char*)Hlds + (d0 ^ (((d0 >> 11) & 7) << 4))) = hvA0.v;
        *(bf16x8_t*)((char*)Hlds + (d1 ^ (((d1 >> 11) & 7) << 4))) = hvA1.v;
        *(bf16x8_t*)((char*)Hlds + (d2 ^ (((d2 >> 11) & 7) << 4))) = hvA2.v;
        *(bf16x8_t*)((char*)Hlds + (d3 ^ (((d3 >> 11) & 7) << 4))) = hvA3.v;
      }
    }
    __syncthreads();

    // ---- MFMA chain A ----
    f32x4_t ac0 = {0,0,0,0}, ac1 = {0,0,0,0}, ac2 = {0,0,0,0}, ac3 = {0,0,0,0};
    #pragma unroll
    for (int ks = 0; ks < 32; ks += 2) {
      bf16x8_t a0 = *(const bf16x8_t*)((const char*)Hlds + ((abase + (ks+0)*64) ^ amask));
      bf16x8_t a1 = *(const bf16x8_t*)((const char*)Hlds + ((abase + (ks+1)*64) ^ amask));
      ac0 = MFMA_(a0, wf[ks],          ac0);
      ac1 = MFMA_(a0, wf[32 + ks],     ac1);
      ac2 = MFMA_(a1, wf[ks + 1],      ac2);
      ac3 = MFMA_(a1, wf[32 + ks + 1], ac3);
    }
    {
      f32x4_t s0 = ac0 + ac2, s1 = ac1 + ac3;
      if ((l >> 4) < 2) {
        int r0 = (l >> 4) * 4, cc = l & 15;
        #pragma unroll
        for (int j = 0; j < 4; ++j) {
          Glds[w][r0 + j][cc]      = s0[j];
          Glds[w][r0 + j][16 + cc] = s1[j];
        }
      }
    }
    __syncthreads();

    // ---- validate + stage chain B (loads landed during A's work) ----
    if (t > 0) {
      asm volatile("s_waitcnt vmcnt(0)" ::: "memory");
      unsigned int bad = 0;
      bad |= (hvB0.u[0]==SENTW)|(hvB0.u[1]==SENTW)|(hvB0.u[2]==SENTW)|(hvB0.u[3]==SENTW);
      bad |= (hvB1.u[0]==SENTW)|(hvB1.u[1]==SENTW)|(hvB1.u[2]==SENTW)|(hvB1.u[3]==SENTW);
      bad |= (hvB2.u[0]==SENTW)|(hvB2.u[1]==SENTW)|(hvB2.u[2]==SENTW)|(hvB2.u[3]==SENTW);
      bad |= (hvB3.u[0]==SENTW)|(hvB3.u[1]==SENTW)|(hvB3.u[2]==SENTW)|(hvB3.u[3]==SENTW);
      while (bad) {    // rare: B published at same wall-time as A
        __builtin_amdgcn_s_sleep(1);
        asm volatile("global_load_dwordx4 %0, %1, off sc0 sc1" : "=v"(hvB0.v)
                     : "v"((unsigned long long)(rsrcB + (size_t)(0 * 256 + tid) * 16)) : "memory");
        asm volatile("global_load_dwordx4 %0, %1, off sc0 sc1" : "=v"(hvB1.v)
                     : "v"((unsigned long long)(rsrcB + (size_t)(1 * 256 + tid) * 16)) : "memory");
        asm volatile("global_load_dwordx4 %0, %1, off sc0 sc1" : "=v"(hvB2.v)
                     : "v"((unsigned long long)(rsrcB + (size_t)(2 * 256 + tid) * 16)) : "memory");
        asm volatile("global_load_dwordx4 %0, %1, off sc0 sc1" : "=v"(hvB3.v)
                     : "v"((unsigned long long)(rsrcB + (size_t)(3 * 256 + tid) * 16)) : "memory");
        asm volatile("s_waitcnt vmcnt(0)" ::: "memory");
        bad = 0;
        bad |= (hvB0.u[0]==SENTW)|(hvB0.u[1]==SENTW)|(hvB0.u[2]==SENTW)|(hvB0.u[3]==SENTW);
        bad |= (hvB1.u[0]==SENTW)|(hvB1.u[1]==SENTW)|(hvB1.u[2]==SENTW)|(hvB1.u[3]==SENTW);
        bad |= (hvB2.u[0]==SENTW)|(hvB2.u[1]==SENTW)|(hvB2.u[2]==SENTW)|(hvB2.u[3]==SENTW);
        bad |= (hvB3.u[0]==SENTW)|(hvB3.u[1]==SENTW)|(hvB3.u[2]==SENTW)|(hvB3.u[3]==SENTW);
      }
      __builtin_amdgcn_sched_barrier(0);
      {
        int d0 = (0 * 256 + tid) * 16, d1 = (1 * 256 + tid) * 16;
        int d2 = (2 * 256 + tid) * 16, d3 = (3 * 256 + tid) * 16;
        *(bf16x8_t*)((char*)Hlds + (d0 ^ (((d0 >> 11) & 7) << 4))) = hvB0.v;
        *(bf16x8_t*)((char*)Hlds + (d1 ^ (((d1 >> 11) & 7) << 4))) = hvB1.v;
        *(bf16x8_t*)((char*)Hlds + (d2 ^ (((d2 >> 11) & 7) << 4))) = hvB2.v;
        *(bf16x8_t*)((char*)Hlds + (d3 ^ (((d3 >> 11) & 7) << 4))) = hvB3.v;
      }
    }

    // ---- epilogue + publish chain A ----
    {
      float pre0 = Glds[0][eb][en] + bf2f(xA0);
      float pre1 = Glds[1][eb][en] + bf2f(xA1);
      float pre2 = Glds[2][eb][en] + bf2f(xA2);
      float pre3 = Glds[3][eb][en] + bf2f(xA3);
      float ig = sigmoidf_(pre0);
      float fg = sigmoidf_(pre1);
      float gg = tanhf_(pre2);
      float og = sigmoidf_(pre3);
      cregA = fg * cregA + ig * gg;
      float hv = og * tanhf_(cregA);
      if (t == T_STEPS - 1) {
        out[((size_t)t * BATCH + b0A + eb) * HID + n0 + en] = hv;
        hT[ciA] = hv;
        cT[ciA] = cregA;
      } else {
        unsigned short mybf = f2bf(hv);
        unsigned short pbf = (unsigned short)(unsigned int)
            __shfl_xor((int)(unsigned int)mybf, 1, 64);
        if ((l & 1) == 0) {
          unsigned int pk = ((unsigned int)mybf) | (((unsigned int)pbf) << 16);
          unsigned short* rdst = ring + (size_t)(t & (RING - 1)) * BATCH * HID;
          __hip_atomic_store((unsigned int*)(rdst + ciA), pk,
                             __ATOMIC_RELAXED, __HIP_MEMORY_SCOPE_AGENT);
          unsigned short* rrst = ring + (size_t)((t + 32) & (RING - 1)) * BATCH * HID;
          __hip_atomic_store((unsigned int*)(rrst + ciA), SENTW,
                             __ATOMIC_RELAXED, __HIP_MEMORY_SCOPE_AGENT);
        }
        out[((size_t)t * BATCH + b0A + eb) * HID + n0 + en] = hv;
      }
    }
    __syncthreads();

    // ---- MFMA chain B ----
    f32x4_t bc0 = {0,0,0,0}, bc1 = {0,0,0,0}, bc2 = {0,0,0,0}, bc3 = {0,0,0,0};
    #pragma unroll
    for (int ks = 0; ks < 32; ks += 2) {
      bf16x8_t a0 = *(const bf16x8_t*)((const char*)Hlds + ((abase + (ks+0)*64) ^ amask));
      bf16x8_t a1 = *(const bf16x8_t*)((const char*)Hlds + ((abase + (ks+1)*64) ^ amask));
      bc0 = MFMA_(a0, wf[ks],          bc0);
      bc1 = MFMA_(a0, wf[32 + ks],     bc1);
      bc2 = MFMA_(a1, wf[ks + 1],      bc2);
      bc3 = MFMA_(a1, wf[32 + ks + 1], bc3);
    }
    {
      f32x4_t s0 = bc0 + bc2, s1 = bc1 + bc3;
      if ((l >> 4) < 2) {
        int r0 = (l >> 4) * 4, cc = l & 15;
        #pragma unroll
        for (int j = 0; j < 4; ++j) {
          Glds[w][r0 + j][cc]      = s0[j];
          Glds[w][r0 + j][16 + cc] = s1[j];
        }
      }
    }
    __syncthreads();

    // ---- epilogue + publish chain B ----
    {
      float pre0 = Glds[0][eb][en] + bf2f(xB0);
      float pre1 = Glds[1][eb][en] + bf2f(xB1);
      float pre2 = Glds[2][eb][en] + bf2f(xB2);
      float pre3 = Glds[3][eb][en] + bf2f(xB3);
      float ig = sigmoidf_(pre0);
      float fg = sigmoidf_(pre1);
      float gg = tanhf_(pre2);
      float og = sigmoidf_(pre3);
      cregB = fg * cregB + ig * gg;
      float hv = og * tanhf_(cregB);
      if (t == T_STEPS - 1) {
        out[((size_t)t * BATCH + b0B + eb) * HID + n0 + en] = hv;
        hT[ciB] = hv;
        cT[ciB] = cregB;
      } else {
        unsigned short mybf = f2bf(hv);
        unsigned short pbf = (unsigned short)(unsigned int)
            __shfl_xor((int)(unsigned int)mybf, 1, 64);
        if ((l & 1) == 0) {
          unsigned int pk = ((unsigned int)mybf) | (((unsigned int)pbf) << 16);
          unsigned short* rdst = ring + (size_t)(t & (RING - 1)) * BATCH * HID;
          __hip_atomic_store((unsigned int*)(rdst + ciB), pk,
                             __ATOMIC_RELAXED, __HIP_MEMORY_SCOPE_AGENT);
          unsigned short* rrst = ring + (size_t)((t + 32) & (RING - 1)) * BATCH * HID;
          __hip_atomic_store((unsigned int*)(rrst + ciB), SENTW,
                             __ATOMIC_RELAXED, __HIP_MEMORY_SCOPE_AGENT);
        }
        out[((size_t)t * BATCH + b0B + eb) * HID + n0 + en] = hv;
      }
    }
    // next iteration's first __syncthreads orders Hlds reuse
  }
}

// ---------------- fallback per-timestep kernel (small ws / coop rejected) ----------------
__global__ __launch_bounds__(256) void k_step_fused(
    const unsigned short* __restrict__ hprev,
    unsigned short* __restrict__ hnext,
    float* __restrict__ cstate,
    const unsigned short* __restrict__ Whh,
    const unsigned short* __restrict__ Wih,
    const float* __restrict__ x,
    const float* __restrict__ bias,
    float* __restrict__ out,
    float* __restrict__ hT, float* __restrict__ cT,
    int t, int is_last)
{
  const int RS = 1560;
  const int XB = 1032;
  __shared__ unsigned short Hlds[16 * RS];
  __shared__ float Glds[4][16][17];
  const int tid = threadIdx.x;
  const int w = tid >> 6, l = tid & 63;
  const int bg = blockIdx.x >> 6, hs = blockIdx.x & 63;
  const int b0 = bg * 16, n0 = hs * 16;

  #pragma unroll
  for (int it = 0; it < 8; ++it) {
    int chunk = tid + it * 256;
    int row = chunk >> 7;
    int cc  = (chunk & 127) * 8;
    *(bf16x8_t*)&Hlds[row * RS + cc] =
        *(const bf16x8_t*)(hprev + (size_t)(b0 + row) * HID + cc);
  }
  #pragma unroll
  for (int it = 0; it < 4; ++it) {
    int chunk = tid + it * 256;
    int row = chunk >> 6;
    int cc  = (chunk & 63) * 8;
    const float* src = x + ((size_t)t * BATCH + b0 + row) * IN + cc;
    float4 f0 = *(const float4*)(src);
    float4 f1 = *(const float4*)(src + 4);
    union { bf16x8_t v; unsigned short s[8]; } u;
    u.s[0]=f2bf(f0.x); u.s[1]=f2bf(f0.y); u.s[2]=f2bf(f0.z); u.s[3]=f2bf(f0.w);
    u.s[4]=f2bf(f1.x); u.s[5]=f2bf(f1.y); u.s[6]=f2bf(f1.z); u.s[7]=f2bf(f1.w);
    *(bf16x8_t*)&Hlds[row * RS + XB + cc] = u.v;
  }
  __syncthreads();

  f32x4_t acc = {0.f, 0.f, 0.f, 0.f};
  const int gcol = (w << 10) + n0 + (l & 15);
  const unsigned short* wp = Whh + (size_t)gcol * HID + ((l >> 4) * 8);
  const unsigned short* ap = &Hlds[(l & 15) * RS + ((l >> 4) * 8)];
  #pragma unroll 4
  for (int ks = 0; ks < 32; ++ks) {
    bf16x8_t a = *(const bf16x8_t*)(ap);
    bf16x8_t b = *(const bf16x8_t*)(wp);
    acc = __builtin_amdgcn_mfma_f32_16x16x32_bf16(a, b, acc, 0, 0, 0);
    ap += 32; wp += 32;
  }
  const unsigned short* wpx = Wih + (size_t)gcol * IN + ((l >> 4) * 8);
  const unsigned short* apx = &Hlds[(l & 15) * RS + XB + ((l >> 4) * 8)];
  #pragma unroll 4
  for (int ks = 0; ks < 16; ++ks) {
    bf16x8_t a = *(const bf16x8_t*)(apx);
    bf16x8_t b = *(const bf16x8_t*)(wpx);
    acc = __builtin_amdgcn_mfma_f32_16x16x32_bf16(a, b, acc, 0, 0, 0);
    apx += 32; wpx += 32;
  }

  {
    int r0 = (l >> 4) * 4, cc = l & 15;
    Glds[w][r0 + 0][cc] = acc[0];
    Glds[w][r0 + 1][cc] = acc[1];
    Glds[w][r0 + 2][cc] = acc[2];
    Glds[w][r0 + 3][cc] = acc[3];
  }
  __syncthreads();

  int b = tid >> 4, n = tid & 15;
  float pre[4];
  #pragma unroll
  for (int g = 0; g < 4; ++g)
    pre[g] = Glds[g][b][n] + bias[(g << 10) + n0 + n];
  float ig = sigmoidf_(pre[0]);
  float fg = sigmoidf_(pre[1]);
  float gg = tanhf_(pre[2]);
  float og = sigmoidf_(pre[3]);
  size_t ci = (size_t)(b0 + b) * HID + n0 + n;
  float cn = fg * cstate[ci] + ig * gg;
  float hv = og * tanhf_(cn);
  cstate[ci] = cn;
  out[((size_t)t * BATCH + b0 + b) * HID + n0 + n] = hv;
  hnext[ci] = f2bf(hv);
  if (is_last) { hT[ci] = hv; cT[ci] = cn; }
}

// ---------------- host launch ----------------
extern "C" void kernel_launch(void* const* d_in, const int* in_sizes, int n_in,
                              void* d_out, int out_size, void* d_ws, size_t ws_size,
                              hipStream_t stream) {
  const float* x    = (const float*)d_in[0];
  const float* Wihf = (const float*)d_in[1];
  const float* bih  = (const float*)d_in[2];
  const float* Whhf = (const float*)d_in[3];
  const float* bhh  = (const float*)d_in[4];
  float* out = (float*)d_out;

  char* ws = (char*)d_ws;
  size_t off = 0;
  auto take = [&](size_t bytes) {
    char* p = ws + off;
    off = (off + bytes + 255) & ~(size_t)255;
    return p;
  };
  unsigned short* wih_b = (unsigned short*)take((size_t)GDIM * IN * 2);   // 4 MB
  unsigned short* whh_b = (unsigned short*)take((size_t)GDIM * HID * 2);  // 8 MB
  float*          bias  = (float*)take((size_t)GDIM * 4);
  unsigned short* h0    = (unsigned short*)take((size_t)BATCH * HID * 2);
  unsigned short* h1    = (unsigned short*)take((size_t)BATCH * HID * 2);
  float*          cbuf  = (float*)take((size_t)BATCH * HID * 4);
  unsigned short* ring  = (unsigned short*)take((size_t)RING * BATCH * HID * 2); // 8 MB
  unsigned short* xproj = (unsigned short*)take((size_t)MROWS * GDIM * 2); // 256 MB
  size_t full_need = off;
  const int primary = (ws_size >= full_need) ? 1 : 0;
  (void)in_sizes; (void)n_in; (void)out_size;

  k_cvt<<<(GDIM * IN / 4 + 255) / 256, 256, 0, stream>>>(Wihf, wih_b, GDIM * IN);
  k_cvt<<<(GDIM * HID / 4 + 255) / 256, 256, 0, stream>>>(Whhf, whh_b, GDIM * HID);
  k_bias<<<(GDIM + 255) / 256, 256, 0, stream>>>(bih, bhh, bias);
  (void)hipMemsetAsync(h0, 0, (size_t)BATCH * HID * 2, stream);

  float* hT = out + (size_t)T_STEPS * BATCH * HID;
  float* cT = hT + (size_t)BATCH * HID;

  if (primary) {
    (void)hipMemsetAsync(ring, 0x7F, (size_t)RING * BATCH * HID * 2, stream);
    k_xproj<<<dim3(GDIM / 128, MROWS / 128), 256, 0, stream>>>(x, wih_b, bias, xproj);
    void* p_xproj = (void*)xproj; void* p_whh = (void*)whh_b;
    void* p_ring = (void*)ring;   void* p_out = (void*)out;
    void* p_hT = (void*)hT;       void* p_cT = (void*)cT;
    void* args[6] = {&p_xproj, &p_whh, &p_ring, &p_out, &p_hT, &p_cT};
    hipError_t err = hipLaunchCooperativeKernel((const void*)k_lstm_persist,
                                                dim3(128), dim3(256), args, 0, stream);
    if (err == hipSuccess) return;
    // fall through to per-step fallback if the cooperative launch is rejected
  }

  (void)hipMemsetAsync(cbuf, 0, (size_t)BATCH * HID * 4, stream);
  unsigned short* hp = h0;
  unsigned short* hn = h1;
  for (int t = 0; t < T_STEPS; ++t) {
    int last = (t == T_STEPS - 1) ? 1 : 0;
    k_step_fused<<<256, 256, 0, stream>>>(hp, hn, cbuf, whh_b, wih_b, x, bias,
                                          out, hT, cT, t, last);
    unsigned short* tmp = hp; hp = hn; hn = tmp;
  }
}

// Round 15
// 1941.856 us; speedup vs baseline: 1.3891x; 1.3891x over previous
//
#include <hip/hip_runtime.h>

#define T_STEPS 512
#define BATCH   64
#define IN      512
#define HID     1024
#define GDIM    4096
#define MROWS   (T_STEPS * BATCH)

typedef __attribute__((ext_vector_type(8))) short bf16x8_t;
typedef __attribute__((ext_vector_type(4))) float f32x4_t;

__device__ __forceinline__ unsigned short f2bf(float f) {
  union { float f; unsigned int u; } v; v.f = f;
  unsigned int r = v.u + 0x7FFFu + ((v.u >> 16) & 1u);
  return (unsigned short)(r >> 16);
}
__device__ __forceinline__ float bf2f(unsigned short u) {
  union { unsigned int u; float f; } v; v.u = ((unsigned int)u) << 16;
  return v.f;
}
__device__ __forceinline__ float sigmoidf_(float x) {
  return 1.0f / (1.0f + __expf(-x));
}
__device__ __forceinline__ float tanhf_(float x) {
  return 1.0f - 2.0f / (__expf(2.0f * x) + 1.0f);
}
__device__ __forceinline__ f32x4_t MFMA_(bf16x8_t a, bf16x8_t b, f32x4_t c) {
  return __builtin_amdgcn_mfma_f32_16x16x32_bf16(a, b, c, 0, 0, 0);
}
__device__ __forceinline__ void gload16(const void* g, void* l) {
  __builtin_amdgcn_global_load_lds(
      (const __attribute__((address_space(1))) unsigned int*)g,
      (__attribute__((address_space(3))) unsigned int*)l, 16, 0, 0);
}

// ---------------- fp32 -> bf16 conversion ----------------
__global__ void k_cvt(const float* __restrict__ src, unsigned short* __restrict__ dst, int n) {
  int i = (blockIdx.x * blockDim.x + threadIdx.x) * 4;
  if (i + 3 < n) {
    float4 f = *(const float4*)(src + i);
    ushort4 o;
    o.x = f2bf(f.x); o.y = f2bf(f.y); o.z = f2bf(f.z); o.w = f2bf(f.w);
    *(ushort4*)(dst + i) = o;
  }
}

__global__ void k_bias(const float* __restrict__ a, const float* __restrict__ b,
                       float* __restrict__ o) {
  int i = blockIdx.x * blockDim.x + threadIdx.x;
  if (i < GDIM) o[i] = a[i] + b[i];
}

// ---------------- x_proj GEMM v2 (m97 recipe): bf16 x @ W_ih^T ----------------
// A = x_b [32768 x 512] bf16 row-major, B = W_ih [4096 x 512] bf16 row-major.
// 128x128 tile, BK=32, global_load_lds width-16 direct staging (linear LDS),
// 4 waves 2x2, each 64x64 via 4x4 16x16x32 MFMA fragments.
__global__ __launch_bounds__(256) void k_xproj2(
    const unsigned short* __restrict__ xb,
    const unsigned short* __restrict__ Wih,
    const float* __restrict__ bias,
    unsigned short* __restrict__ xproj)
{
  __shared__ __align__(16) unsigned short Alds[128 * 32];  // 8 KB
  __shared__ __align__(16) unsigned short Blds[128 * 32];  // 8 KB
  const int tid = threadIdx.x;
  const int w = tid >> 6, l = tid & 63;
  const int m0 = blockIdx.y * 128, n0 = blockIdx.x * 128;
  const int wm = (w >> 1) * 64, wn = (w & 1) * 64;
  f32x4_t acc[4][4] = {};

  for (int k0 = 0; k0 < IN; k0 += 32) {
    // stage A and B tiles: 8 KB each via global_load_lds (2 passes/thread/matrix)
    #pragma unroll
    for (int p = 0; p < 2; ++p) {
      int chunk = p * 256 + tid;            // 0..511 (16B chunks)
      int row = chunk >> 2;                 // 0..127
      int kc  = (chunk & 3) * 8;            // 0,8,16,24
      char* abase = (char*)Alds + (size_t)(p * 256 + w * 64) * 16;  // wave-uniform
      char* bbase = (char*)Blds + (size_t)(p * 256 + w * 64) * 16;
      gload16(xb  + (size_t)(m0 + row) * IN + k0 + kc, abase);
      gload16(Wih + (size_t)(n0 + row) * IN + k0 + kc, bbase);
    }
    __syncthreads();   // compiler emits vmcnt(0) drain before barrier

    bf16x8_t a[4], b[4];
    #pragma unroll
    for (int i = 0; i < 4; ++i)
      a[i] = *(const bf16x8_t*)&Alds[(wm + i * 16 + (l & 15)) * 32 + ((l >> 4) * 8)];
    #pragma unroll
    for (int i = 0; i < 4; ++i)
      b[i] = *(const bf16x8_t*)&Blds[(wn + i * 16 + (l & 15)) * 32 + ((l >> 4) * 8)];
    #pragma unroll
    for (int mi = 0; mi < 4; ++mi) {
      #pragma unroll
      for (int ni = 0; ni < 4; ++ni)
        acc[mi][ni] = MFMA_(a[mi], b[ni], acc[mi][ni]);
    }
    __syncthreads();
  }
  // epilogue (verified layout): D row = (l>>4)*4 + r, col = l&15
  #pragma unroll
  for (int ni = 0; ni < 4; ++ni) {
    int col = n0 + wn + ni * 16 + (l & 15);
    float bv = bias[col];
    #pragma unroll
    for (int mi = 0; mi < 4; ++mi) {
      int rbase = m0 + wm + mi * 16 + (l >> 4) * 4;
      #pragma unroll
      for (int r = 0; r < 4; ++r)
        xproj[(size_t)(rbase + r) * GDIM + col] = f2bf(acc[mi][ni][r] + bv);
    }
  }
}

// ---------------- persistent recurrence kernel (R11, best validated) ----------------
// 256 blocks x 256 threads: blockIdx = grp*32 + slot. Group grp owns batches
// [grp*8,+8); block owns hidden cols [slot*32,+32) x 4 gates. Wave = gate,
// 2 col-tiles of 16, 64 W_hh frags resident in AGPRs. MFMA M=16 with batch
// rows 8..15 zero-padded in LDS. All cross-block traffic: relaxed-agent
// atomics / sc0 sc1 (coherence point; NO acquire/release = no L2 flush).
// Handshake: per-step monotonic counter bar[grp*512+t]; producers drain
// (vmcnt 0) -> __syncthreads -> tid0 fetch_add; consumer tid0-only poll.
__global__ __launch_bounds__(256, 1) void k_lstm_persist(
    const unsigned short* __restrict__ xproj,
    const unsigned short* __restrict__ Whh,
    unsigned short* __restrict__ hbuf0,
    unsigned short* __restrict__ hbuf1,
    float* __restrict__ out,
    float* __restrict__ hT,
    float* __restrict__ cT,
    unsigned int* __restrict__ bar)
{
  __shared__ __align__(16) unsigned short Hlds[16384];  // 16 x 1024 bf16; rows 8..15 stay zero
  __shared__ float Glds[4][8][33];

  const int tid = threadIdx.x;
  const int w = tid >> 6, l = tid & 63;
  const int grp  = blockIdx.x >> 5;     // batch group 0..7 (8 batches each)
  const int slot = blockIdx.x & 31;     // col slice 0..31 (32 cols each)
  const int b0 = grp * 8, n0 = slot * 32;

  {
    bf16x8_t zv = {0, 0, 0, 0, 0, 0, 0, 0};
    #pragma unroll
    for (int i = 0; i < 8; ++i)
      *(bf16x8_t*)((char*)Hlds + (size_t)(i * 256 + tid) * 16) = zv;
  }
  __syncthreads();

  bf16x8_t wf[64];
  {
    const unsigned short* wp0 =
        Whh + (size_t)((w << 10) + n0 + (l & 15)) * HID + ((l >> 4) * 8);
    const unsigned short* wp1 = wp0 + (size_t)16 * HID;
    #pragma unroll
    for (int ks = 0; ks < 32; ++ks) {
      wf[ks]      = *(const bf16x8_t*)(wp0 + ks * 32);
      wf[32 + ks] = *(const bf16x8_t*)(wp1 + ks * 32);
    }
  }

  const int eb = tid >> 5, en = tid & 31;
  const size_t ci = (size_t)(b0 + eb) * HID + n0 + en;
  float creg = 0.0f;

  const int abase = (l & 15) * 2048 + ((l >> 4) * 16);
  const int amask = (l & 7) << 4;

  unsigned int* const fgrp = bar + grp * 512;

  #pragma unroll 1
  for (int t = 0; t < T_STEPS; ++t) {
    const unsigned short* hc = (t & 1) ? hbuf1 : hbuf0;
    unsigned short*       hn = (t & 1) ? hbuf0 : hbuf1;

    const unsigned short* xpp = xproj + ((size_t)t * BATCH + b0 + eb) * GDIM + n0 + en;
    unsigned short x0 = xpp[0], x1 = xpp[1024], x2 = xpp[2048], x3 = xpp[3072];
    asm volatile("" ::: "memory");

    if (t > 0) {
      if (tid == 0) {
        const unsigned int* f = fgrp + (t - 1);
        while (__hip_atomic_load(f, __ATOMIC_RELAXED, __HIP_MEMORY_SCOPE_AGENT) < 32u)
          __builtin_amdgcn_s_sleep(1);
      }
      __syncthreads();
    }

    {
      const char* hsrc = (const char*)(hc + (size_t)b0 * HID);
      bf16x8_t hv[4];
      #pragma unroll
      for (int i = 0; i < 4; ++i) {
        unsigned long long ap = (unsigned long long)(hsrc + (size_t)(i * 256 + tid) * 16);
        asm volatile("global_load_dwordx4 %0, %1, off sc0 sc1"
                     : "=v"(hv[i]) : "v"(ap) : "memory");
      }
      asm volatile("s_waitcnt vmcnt(0)" ::: "memory");
      __builtin_amdgcn_sched_barrier(0);
      #pragma unroll
      for (int i = 0; i < 4; ++i) {
        int d = (i * 256 + tid) * 16;
        int sd = d ^ (((d >> 11) & 7) << 4);
        *(bf16x8_t*)((char*)Hlds + sd) = hv[i];
      }
    }
    __syncthreads();

    f32x4_t ac0 = {0,0,0,0}, ac1 = {0,0,0,0}, ac2 = {0,0,0,0}, ac3 = {0,0,0,0};
    #pragma unroll
    for (int ks = 0; ks < 32; ks += 2) {
      bf16x8_t a0 = *(const bf16x8_t*)((const char*)Hlds + ((abase + (ks+0)*64) ^ amask));
      bf16x8_t a1 = *(const bf16x8_t*)((const char*)Hlds + ((abase + (ks+1)*64) ^ amask));
      ac0 = MFMA_(a0, wf[ks],          ac0);
      ac1 = MFMA_(a0, wf[32 + ks],     ac1);
      ac2 = MFMA_(a1, wf[ks + 1],      ac2);
      ac3 = MFMA_(a1, wf[32 + ks + 1], ac3);
    }
    f32x4_t s0 = ac0 + ac2;
    f32x4_t s1 = ac1 + ac3;

    if ((l >> 4) < 2) {
      int r0 = (l >> 4) * 4, cc = l & 15;
      #pragma unroll
      for (int j = 0; j < 4; ++j) {
        Glds[w][r0 + j][cc]      = s0[j];
        Glds[w][r0 + j][16 + cc] = s1[j];
      }
    }
    __syncthreads();

    float pre0 = Glds[0][eb][en] + bf2f(x0);
    float pre1 = Glds[1][eb][en] + bf2f(x1);
    float pre2 = Glds[2][eb][en] + bf2f(x2);
    float pre3 = Glds[3][eb][en] + bf2f(x3);
    float ig = sigmoidf_(pre0);
    float fg = sigmoidf_(pre1);
    float gg = tanhf_(pre2);
    float og = sigmoidf_(pre3);
    creg = fg * creg + ig * gg;
    float hv = og * tanhf_(creg);

    if (t == T_STEPS - 1) {
      out[((size_t)t * BATCH + b0 + eb) * HID + n0 + en] = hv;
      hT[ci] = hv;
      cT[ci] = creg;
    } else {
      unsigned short mybf = f2bf(hv);
      unsigned short pbf = (unsigned short)(unsigned int)
          __shfl_xor((int)(unsigned int)mybf, 1, 64);
      if ((l & 1) == 0) {
        unsigned int pk = ((unsigned int)mybf) | (((unsigned int)pbf) << 16);
        __hip_atomic_store((unsigned int*)(hn + ci), pk,
                           __ATOMIC_RELAXED, __HIP_MEMORY_SCOPE_AGENT);
      }
      asm volatile("s_waitcnt vmcnt(0)" ::: "memory");
      __syncthreads();
      if (tid == 0)
        (void)__hip_atomic_fetch_add(fgrp + t, 1u,
                                     __ATOMIC_RELAXED, __HIP_MEMORY_SCOPE_AGENT);
      out[((size_t)t * BATCH + b0 + eb) * HID + n0 + en] = hv;
    }
  }
}

// ---------------- fallback per-timestep kernel (small ws / coop rejected) ----------------
__global__ __launch_bounds__(256) void k_step_fused(
    const unsigned short* __restrict__ hprev,
    unsigned short* __restrict__ hnext,
    float* __restrict__ cstate,
    const unsigned short* __restrict__ Whh,
    const unsigned short* __restrict__ Wih,
    const float* __restrict__ x,
    const float* __restrict__ bias,
    float* __restrict__ out,
    float* __restrict__ hT, float* __restrict__ cT,
    int t, int is_last)
{
  const int RS = 1560;
  const int XB = 1032;
  __shared__ unsigned short Hlds[16 * RS];
  __shared__ float Glds[4][16][17];
  const int tid = threadIdx.x;
  const int w = tid >> 6, l = tid & 63;
  const int bg = blockIdx.x >> 6, hs = blockIdx.x & 63;
  const int b0 = bg * 16, n0 = hs * 16;

  #pragma unroll
  for (int it = 0; it < 8; ++it) {
    int chunk = tid + it * 256;
    int row = chunk >> 7;
    int cc  = (chunk & 127) * 8;
    *(bf16x8_t*)&Hlds[row * RS + cc] =
        *(const bf16x8_t*)(hprev + (size_t)(b0 + row) * HID + cc);
  }
  #pragma unroll
  for (int it = 0; it < 4; ++it) {
    int chunk = tid + it * 256;
    int row = chunk >> 6;
    int cc  = (chunk & 63) * 8;
    const float* src = x + ((size_t)t * BATCH + b0 + row) * IN + cc;
    float4 f0 = *(const float4*)(src);
    float4 f1 = *(const float4*)(src + 4);
    union { bf16x8_t v; unsigned short s[8]; } u;
    u.s[0]=f2bf(f0.x); u.s[1]=f2bf(f0.y); u.s[2]=f2bf(f0.z); u.s[3]=f2bf(f0.w);
    u.s[4]=f2bf(f1.x); u.s[5]=f2bf(f1.y); u.s[6]=f2bf(f1.z); u.s[7]=f2bf(f1.w);
    *(bf16x8_t*)&Hlds[row * RS + XB + cc] = u.v;
  }
  __syncthreads();

  f32x4_t acc = {0.f, 0.f, 0.f, 0.f};
  const int gcol = (w << 10) + n0 + (l & 15);
  const unsigned short* wp = Whh + (size_t)gcol * HID + ((l >> 4) * 8);
  const unsigned short* ap = &Hlds[(l & 15) * RS + ((l >> 4) * 8)];
  #pragma unroll 4
  for (int ks = 0; ks < 32; ++ks) {
    bf16x8_t a = *(const bf16x8_t*)(ap);
    bf16x8_t b = *(const bf16x8_t*)(wp);
    acc = __builtin_amdgcn_mfma_f32_16x16x32_bf16(a, b, acc, 0, 0, 0);
    ap += 32; wp += 32;
  }
  const unsigned short* wpx = Wih + (size_t)gcol * IN + ((l >> 4) * 8);
  const unsigned short* apx = &Hlds[(l & 15) * RS + XB + ((l >> 4) * 8)];
  #pragma unroll 4
  for (int ks = 0; ks < 16; ++ks) {
    bf16x8_t a = *(const bf16x8_t*)(apx);
    bf16x8_t b = *(const bf16x8_t*)(wpx);
    acc = __builtin_amdgcn_mfma_f32_16x16x32_bf16(a, b, acc, 0, 0, 0);
    apx += 32; wpx += 32;
  }

  {
    int r0 = (l >> 4) * 4, cc = l & 15;
    Glds[w][r0 + 0][cc] = acc[0];
    Glds[w][r0 + 1][cc] = acc[1];
    Glds[w][r0 + 2][cc] = acc[2];
    Glds[w][r0 + 3][cc] = acc[3];
  }
  __syncthreads();

  int b = tid >> 4, n = tid & 15;
  float pre[4];
  #pragma unroll
  for (int g = 0; g < 4; ++g)
    pre[g] = Glds[g][b][n] + bias[(g << 10) + n0 + n];
  float ig = sigmoidf_(pre[0]);
  float fg = sigmoidf_(pre[1]);
  float gg = tanhf_(pre[2]);
  float og = sigmoidf_(pre[3]);
  size_t ci = (size_t)(b0 + b) * HID + n0 + n;
  float cn = fg * cstate[ci] + ig * gg;
  float hv = og * tanhf_(cn);
  cstate[ci] = cn;
  out[((size_t)t * BATCH + b0 + b) * HID + n0 + n] = hv;
  hnext[ci] = f2bf(hv);
  if (is_last) { hT[ci] = hv; cT[ci] = cn; }
}

// ---------------- host launch ----------------
extern "C" void kernel_launch(void* const* d_in, const int* in_sizes, int n_in,
                              void* d_out, int out_size, void* d_ws, size_t ws_size,
                              hipStream_t stream) {
  const float* x    = (const float*)d_in[0];
  const float* Wihf = (const float*)d_in[1];
  const float* bih  = (const float*)d_in[2];
  const float* Whhf = (const float*)d_in[3];
  const float* bhh  = (const float*)d_in[4];
  float* out = (float*)d_out;

  char* ws = (char*)d_ws;
  size_t off = 0;
  auto take = [&](size_t bytes) {
    char* p = ws + off;
    off = (off + bytes + 255) & ~(size_t)255;
    return p;
  };
  unsigned short* wih_b = (unsigned short*)take((size_t)GDIM * IN * 2);   // 4 MB
  unsigned short* whh_b = (unsigned short*)take((size_t)GDIM * HID * 2);  // 8 MB
  float*          bias  = (float*)take((size_t)GDIM * 4);
  unsigned short* h0    = (unsigned short*)take((size_t)BATCH * HID * 2);
  unsigned short* h1    = (unsigned short*)take((size_t)BATCH * HID * 2);
  float*          cbuf  = (float*)take((size_t)BATCH * HID * 4);
  unsigned int*   bar   = (unsigned int*)take((size_t)8 * 512 * 4);       // [grp][t]
  unsigned short* xb    = (unsigned short*)take((size_t)MROWS * IN * 2);  // 32 MB
  unsigned short* xproj = (unsigned short*)take((size_t)MROWS * GDIM * 2); // 256 MB
  size_t full_need = off;
  const int primary = (ws_size >= full_need) ? 1 : 0;
  (void)in_sizes; (void)n_in; (void)out_size;

  k_cvt<<<(GDIM * IN / 4 + 255) / 256, 256, 0, stream>>>(Wihf, wih_b, GDIM * IN);
  k_cvt<<<(GDIM * HID / 4 + 255) / 256, 256, 0, stream>>>(Whhf, whh_b, GDIM * HID);
  k_bias<<<(GDIM + 255) / 256, 256, 0, stream>>>(bih, bhh, bias);
  (void)hipMemsetAsync(h0, 0, (size_t)BATCH * HID * 2, stream);

  float* hT = out + (size_t)T_STEPS * BATCH * HID;
  float* cT = hT + (size_t)BATCH * HID;

  if (primary) {
    (void)hipMemsetAsync(bar, 0, (size_t)8 * 512 * 4, stream);
    k_cvt<<<(MROWS * IN / 4 + 255) / 256, 256, 0, stream>>>(x, xb, MROWS * IN);
    k_xproj2<<<dim3(GDIM / 128, MROWS / 128), 256, 0, stream>>>(xb, wih_b, bias, xproj);
    void* p_xproj = (void*)xproj; void* p_whh = (void*)whh_b;
    void* p_h0 = (void*)h0;       void* p_h1 = (void*)h1;
    void* p_out = (void*)out;     void* p_hT = (void*)hT;
    void* p_cT = (void*)cT;       void* p_fl = (void*)bar;
    void* args[8] = {&p_xproj, &p_whh, &p_h0, &p_h1, &p_out, &p_hT, &p_cT, &p_fl};
    hipError_t err = hipLaunchCooperativeKernel((const void*)k_lstm_persist,
                                                dim3(256), dim3(256), args, 0, stream);
    if (err == hipSuccess) return;
    // fall through to per-step fallback if the cooperative launch is rejected
  }

  (void)hipMemsetAsync(cbuf, 0, (size_t)BATCH * HID * 4, stream);
  unsigned short* hp = h0;
  unsigned short* hn = h1;
  for (int t = 0; t < T_STEPS; ++t) {
    int last = (t == T_STEPS - 1) ? 1 : 0;
    k_step_fused<<<256, 256, 0, stream>>>(hp, hn, cbuf, whh_b, wih_b, x, bias,
                                          out, hT, cT, t, last);
    unsigned short* tmp = hp; hp = hn; hn = tmp;
  }
}